// Round 1
// baseline (1711.989 us; speedup 1.0000x reference)
//
#include <hip/hip_runtime.h>
#include <math.h>

// Problem constants
#define NB   32
#define C    8
#define D    4
#define H    256
#define W    256
#define DP   2
#define HP   128
#define WP   128
#define MC   16          // DP*C merged channels
#define HO   126
#define WO   126
#define PATCH 144        // MC*3*3
#define OUTD 128
#define NL   (HO*WO)     // 15876 patches per image

// ---------------- Kernel 1: LPPool3d (p=2, 2x2x2) + depth->channel merge -------------
// merged[n][mc][hp][wp], mc = dp*C + c
__global__ void pool_kernel(const float* __restrict__ x, float* __restrict__ merged) {
    int idx = blockIdx.x;
    int hp = idx & (HP - 1);
    int mc = (idx >> 7) & (MC - 1);
    int n  = idx >> 11;
    int wp = threadIdx.x;

    int dp = mc >> 3;
    int c  = mc & 7;

    const float* xb = x + ((((size_t)n * C + c) * D + 2 * dp) * H + 2 * hp) * W + 2 * wp;
    float s = 0.f;
#pragma unroll
    for (int dd = 0; dd < 2; dd++) {
#pragma unroll
        for (int hh = 0; hh < 2; hh++) {
            float2 v = *(const float2*)(xb + (size_t)dd * H * W + hh * W);
            s += v.x * v.x + v.y * v.y;
        }
    }
    merged[(((size_t)n * MC + mc) * HP + hp) * WP + wp] = sqrtf(s);
}

// ---------------- Kernel 2: per-patch linear + CELU + accumulate over patches --------
// One block per (n, ho). Thread t handles patch (ho, wo=t). Patch values held in VGPRs;
// weights read via uniform (scalar) loads inside the o-loop. Wave-reduce + atomicAdd.
__global__ void gemm_kernel(const float* __restrict__ merged,
                            const float* __restrict__ lin_w,
                            const float* __restrict__ lin_b,
                            float* __restrict__ acc) {
    int ho = blockIdx.x % HO;
    int n  = blockIdx.x / HO;
    int t  = threadIdx.x;            // 0..127
    int lane = t & 63;

    __shared__ float tile[MC * 3 * WP];   // 24 KB: merged[n][:, ho..ho+2, :]

    // cooperative coalesced load, float4
    const int nq = MC * 3 * WP / 4;       // 1536 float4
    for (int q = t; q < nq; q += 128) {
        int row = q >> 5;                 // 0..47  (mc*3+i)
        int col = q & 31;                 // float4 within 128-wide row
        int mc = row / 3, i = row - 3 * mc;
        ((float4*)tile)[q] =
            ((const float4*)(merged + (((size_t)n * MC + mc) * HP + (ho + i)) * WP))[col];
    }
    __syncthreads();

    bool valid = (t < WO);
    int tt = valid ? t : 0;

    float m[PATCH];
#pragma unroll
    for (int mc = 0; mc < MC; mc++) {
#pragma unroll
        for (int i = 0; i < 3; i++) {
#pragma unroll
            for (int j = 0; j < 3; j++) {
                m[mc * 9 + i * 3 + j] = tile[(mc * 3 + i) * WP + tt + j];
            }
        }
    }

    for (int o = 0; o < OUTD; o++) {
        const float* wrow = lin_w + o * PATCH;   // uniform -> scalar loads
        float p0 = 0.f, p1 = 0.f, p2 = 0.f, p3 = 0.f;
#pragma unroll
        for (int k = 0; k < PATCH; k += 4) {
            p0 += m[k + 0] * wrow[k + 0];
            p1 += m[k + 1] * wrow[k + 1];
            p2 += m[k + 2] * wrow[k + 2];
            p3 += m[k + 3] * wrow[k + 3];
        }
        float p = ((p0 + p1) + (p2 + p3)) + lin_b[o];
        float a = (p > 0.f) ? p : (__expf(p) - 1.f);   // CELU(alpha=1)
        if (!valid) a = 0.f;
#pragma unroll
        for (int off = 32; off > 0; off >>= 1) a += __shfl_down(a, off, 64);
        if (lane == 0) atomicAdd(&acc[n * OUTD + o], a);
    }
}

// ---------------- Kernel 3: mean + clamped L2 normalize ------------------------------
__global__ void finalize_kernel(const float* __restrict__ acc, float* __restrict__ out) {
    int n = blockIdx.x;
    int o = threadIdx.x;     // 128 threads
    float a = acc[n * OUTD + o] * (1.0f / (float)NL);
    float s = a * a;
#pragma unroll
    for (int off = 32; off > 0; off >>= 1) s += __shfl_down(s, off, 64);
    __shared__ float partial[2];
    if ((o & 63) == 0) partial[o >> 6] = s;
    __syncthreads();
    float norm = sqrtf(partial[0] + partial[1]);
    norm = fmaxf(norm, 1e-6f);
    out[n * OUTD + o] = a / norm;
}

extern "C" void kernel_launch(void* const* d_in, const int* in_sizes, int n_in,
                              void* d_out, int out_size, void* d_ws, size_t ws_size,
                              hipStream_t stream) {
    const float* x     = (const float*)d_in[0];
    const float* lin_w = (const float*)d_in[1];
    const float* lin_b = (const float*)d_in[2];
    float* out = (float*)d_out;

    float* acc    = (float*)d_ws;            // 32*128 floats = 16 KB
    float* merged = (float*)d_ws + NB * OUTD; // 32*16*128*128 floats = 33.5 MB

    hipMemsetAsync(acc, 0, NB * OUTD * sizeof(float), stream);

    pool_kernel<<<NB * MC * HP, WP, 0, stream>>>(x, merged);
    gemm_kernel<<<NB * HO, 128, 0, stream>>>(merged, lin_w, lin_b, acc);
    finalize_kernel<<<NB, OUTD, 0, stream>>>(acc, out);
}

// Round 2
// 756.229 us; speedup vs baseline: 2.2638x; 2.2638x over previous
//
#include <hip/hip_runtime.h>
#include <math.h>

#define NB   32
#define C    8
#define D    4
#define H    256
#define W    256
#define HP   128
#define WP   128
#define MC   16
#define HO   126
#define WO   126
#define PATCH 144
#define OUTD 128
#define NL   (HO*WO)
#define HOG  3          // ho rows per gemm block (126 = 3*42)
#define AROW 172        // A row stride (bf16): 344 B -> b64-aligned, bank-spread
#define BROW 168        // B row stride (bf16): 336 B -> b128-aligned, bank-spread

typedef float  f32x4  __attribute__((ext_vector_type(4)));
typedef __bf16 bf16x2 __attribute__((ext_vector_type(2)));
typedef __bf16 bf16x4 __attribute__((ext_vector_type(4)));
typedef __bf16 bf16x8 __attribute__((ext_vector_type(8)));

// ---------------- Kernel 1: LPPool3d (p=2, 2x2x2) + depth->channel merge -------------
// merged[n][mc][hp][wp], mc = dp*C + c. 256 thr, 2 outputs/thread, 4 hp rows/block.
__global__ __launch_bounds__(256) void pool_kernel(const float* __restrict__ x,
                                                   float* __restrict__ merged) {
    int b = blockIdx.x;
    int hpq = b & 31;
    int mc  = (b >> 5) & 15;
    int n   = b >> 9;
    int t = threadIdx.x;
    int hp = hpq * 4 + (t >> 6);
    int wp = (t & 63) * 2;
    int dp = mc >> 3, c = mc & 7;

    const float* xb = x + ((((size_t)n * C + c) * D + 2 * dp) * H + 2 * hp) * W + 2 * wp;
    float4 a0 = *(const float4*)(xb);
    float4 a1 = *(const float4*)(xb + W);
    float4 a2 = *(const float4*)(xb + (size_t)H * W);
    float4 a3 = *(const float4*)(xb + (size_t)H * W + W);
    float s0 = a0.x*a0.x + a0.y*a0.y + a1.x*a1.x + a1.y*a1.y
             + a2.x*a2.x + a2.y*a2.y + a3.x*a3.x + a3.y*a3.y;
    float s1 = a0.z*a0.z + a0.w*a0.w + a1.z*a1.z + a1.w*a1.w
             + a2.z*a2.z + a2.w*a2.w + a3.z*a3.z + a3.w*a3.w;
    float2 o2 = make_float2(sqrtf(s0), sqrtf(s1));
    *(float2*)(merged + (((size_t)n * MC + mc) * HP + hp) * WP + wp) = o2;
}

// ---------------- Kernel 2: MFMA im2col GEMM + bias + CELU + patch-reduce ------------
__global__ __launch_bounds__(256, 1)
void gemm_kernel(const float* __restrict__ merged, const float* __restrict__ lin_w,
                 const float* __restrict__ lin_b, float* __restrict__ accg) {
    __shared__ __bf16 Alds[128 * AROW];   // 44032 B: im2col patches, row m=wo
    __shared__ __bf16 Blds[OUTD * BROW];  // 43008 B: weights, row n=o
    __shared__ float  red[4 * OUTD];

    int blk = blockIdx.x;
    int g = blk % (HO / HOG);
    int n = blk / (HO / HOG);
    int t = threadIdx.x;
    int wave = t >> 6, lane = t & 63, quad = lane >> 4, l16 = lane & 15;

    // --- B staging: fp32 W[o][k] -> bf16 Blds[o][k], zero-pad k in [144,168) ---
    for (int q = t; q < OUTD * BROW; q += 256) {
        int o = q / BROW, k = q - o * BROW;
        Blds[q] = (k < PATCH) ? (__bf16)lin_w[o * PATCH + k] : (__bf16)0.f;
    }

    float lb[8];
#pragma unroll
    for (int nt = 0; nt < 8; nt++) lb[nt] = lin_b[nt * 16 + l16];

    float srun[8] = {0.f, 0.f, 0.f, 0.f, 0.f, 0.f, 0.f, 0.f};

    int m_   = t & 127;      // patch row (wo) this thread builds
    int half = t >> 7;       // k-range half
    const float* mbase = merged + (size_t)n * MC * HP * WP;

    for (int hh = 0; hh < HOG; hh++) {
        int ho = g * HOG + hh;

        // --- A staging: Alds[m][k] = merged[n][mc][ho+i][m+j], k = mc*9+i*3+j ---
#pragma unroll
        for (int kk = 0; kk < 43; kk++) {
            int k = half * 86 + kk * 2;
            float v0 = 0.f, v1 = 0.f;
            if (k < PATCH) {
                int mc = k / 9, r = k - mc * 9;
                int i = r / 3, j = r - i * 3;
                int col = m_ + j; col = col < 127 ? col : 127;
                v0 = mbase[((size_t)mc * HP + (ho + i)) * WP + col];
            }
            if (k + 1 < PATCH) {
                int k1 = k + 1;
                int mc = k1 / 9, r = k1 - mc * 9;
                int i = r / 3, j = r - i * 3;
                int col = m_ + j; col = col < 127 ? col : 127;
                v1 = mbase[((size_t)mc * HP + (ho + i)) * WP + col];
            }
            bf16x2 pr = {(__bf16)v0, (__bf16)v1};
            *(bf16x2*)&Alds[m_ * AROW + k] = pr;
        }
        __syncthreads();

        // --- MFMA main: wave handles M-tiles {2w,2w+1} x all 8 N-tiles, K=160 ---
        f32x4 acc[2][8] = {};
#pragma unroll
        for (int ks = 0; ks < 5; ks++) {
            bf16x8 afr[2];
#pragma unroll
            for (int mt = 0; mt < 2; mt++) {
                const __bf16* ap = &Alds[((wave * 2 + mt) * 16 + l16) * AROW + ks * 32 + quad * 8];
                bf16x4 lo = *(const bf16x4*)ap;
                bf16x4 hi = *(const bf16x4*)(ap + 4);
                afr[mt] = __builtin_shufflevector(lo, hi, 0, 1, 2, 3, 4, 5, 6, 7);
            }
#pragma unroll
            for (int nt = 0; nt < 8; nt++) {
                bf16x8 bfr = *(const bf16x8*)&Blds[(nt * 16 + l16) * BROW + ks * 32 + quad * 8];
                acc[0][nt] = __builtin_amdgcn_mfma_f32_16x16x32_bf16(afr[0], bfr, acc[0][nt], 0, 0, 0);
                acc[1][nt] = __builtin_amdgcn_mfma_f32_16x16x32_bf16(afr[1], bfr, acc[1][nt], 0, 0, 0);
            }
        }
        __syncthreads();   // Alds reads done; next iter may overwrite

        // --- epilogue: bias + CELU, mask padded patches, reduce over m ---
#pragma unroll
        for (int nt = 0; nt < 8; nt++) {
            float s = 0.f;
#pragma unroll
            for (int mt = 0; mt < 2; mt++) {
                int mb = (wave * 2 + mt) * 16 + quad * 4;
#pragma unroll
                for (int r = 0; r < 4; r++) {
                    float p = acc[mt][nt][r] + lb[nt];
                    float a = (p > 0.f) ? p : (__expf(p) - 1.f);
                    if (mb + r < WO) s += a;
                }
            }
            s += __shfl_xor(s, 16, 64);
            s += __shfl_xor(s, 32, 64);
            srun[nt] += s;
        }
    }

    if (quad == 0) {
#pragma unroll
        for (int nt = 0; nt < 8; nt++) red[wave * OUTD + nt * 16 + l16] = srun[nt];
    }
    __syncthreads();
    if (t < OUTD) {
        float tot = red[t] + red[OUTD + t] + red[2 * OUTD + t] + red[3 * OUTD + t];
        atomicAdd(&accg[n * OUTD + t], tot);
    }
}

// ---------------- Kernel 3: mean + clamped L2 normalize ------------------------------
__global__ void finalize_kernel(const float* __restrict__ acc, float* __restrict__ out) {
    int n = blockIdx.x;
    int o = threadIdx.x;     // 128 threads
    float a = acc[n * OUTD + o] * (1.0f / (float)NL);
    float s = a * a;
#pragma unroll
    for (int off = 32; off > 0; off >>= 1) s += __shfl_down(s, off, 64);
    __shared__ float partial[2];
    if ((o & 63) == 0) partial[o >> 6] = s;
    __syncthreads();
    float norm = sqrtf(partial[0] + partial[1]);
    norm = fmaxf(norm, 1e-6f);
    out[n * OUTD + o] = a / norm;
}

extern "C" void kernel_launch(void* const* d_in, const int* in_sizes, int n_in,
                              void* d_out, int out_size, void* d_ws, size_t ws_size,
                              hipStream_t stream) {
    const float* x     = (const float*)d_in[0];
    const float* lin_w = (const float*)d_in[1];
    const float* lin_b = (const float*)d_in[2];
    float* out = (float*)d_out;

    float* acc    = (float*)d_ws;              // 32*128 floats
    float* merged = (float*)d_ws + NB * OUTD;  // 33.5 MB

    hipMemsetAsync(acc, 0, NB * OUTD * sizeof(float), stream);

    pool_kernel<<<NB * MC * 32, 256, 0, stream>>>(x, merged);
    gemm_kernel<<<NB * (HO / HOG), 256, 0, stream>>>(merged, lin_w, lin_b, acc);
    finalize_kernel<<<NB, OUTD, 0, stream>>>(acc, out);
}

// Round 3
// 432.822 us; speedup vs baseline: 3.9554x; 1.7472x over previous
//
#include <hip/hip_runtime.h>
#include <math.h>

#define NB   32
#define C    8
#define D    4
#define H    256
#define W    256
#define HP   128
#define WP   128
#define MC   16
#define HO   126
#define WO   126
#define PATCH 144
#define OUTD 128
#define NL   (HO*WO)
#define HOG  6            // output rows per block (126 = 6*21)
#define NGRP (HO/HOG)     // 21
#define PROWS 9           // HOG+2 data rows + 1 zero row (for zero-pad tap 9)
#define BROW 168          // B row stride (bf16): 336 B, b128-aligned, bank-spread

typedef float  f32x4  __attribute__((ext_vector_type(4)));
typedef __bf16 bf16x8 __attribute__((ext_vector_type(8)));

// Fused: LPPool3d(2,2,2,p=2) -> im2col-free MFMA GEMM (K reordered as tap*16+mc)
// -> bias + CELU -> patch-sum -> atomicAdd per (n,o).
__global__ __launch_bounds__(256, 2)
void fused_kernel(const float* __restrict__ x, const float* __restrict__ lin_w,
                  const float* __restrict__ lin_b, float* __restrict__ accg) {
    __shared__ __align__(16) char smem[PROWS*128*32 + OUTD*BROW*2];   // 36864 + 43008 B
    __bf16* Pl   = (__bf16*)smem;                       // P[row][wp][mc], mc contiguous
    __bf16* Blds = (__bf16*)(smem + PROWS*128*32);      // B[o][k_new]

    int blk = blockIdx.x;
    int g = blk % NGRP, n = blk / NGRP;
    int ho0 = g * HOG;
    int t = threadIdx.x;
    int wave = t >> 6, lane = t & 63, quad = lane >> 4, l16 = lane & 15;

    // ---- P staging: pool 2x2x2 from x, write bf16x8 (8 channels) per store ----
    {
        int wp = t & 127, dph = t >> 7;     // dph = dp half (mc = dph*8 + c)
        const float* xn = x + (size_t)n * (C*D*H*W);
#pragma unroll 2
        for (int i = 0; i < 8; i++) {
            int hp = ho0 + i;
            bf16x8 pk;
#pragma unroll
            for (int c = 0; c < 8; c++) {
                const float* xb = xn + ((c*4 + 2*dph) * H + 2*hp) * W + 2*wp;
                float2 a0 = *(const float2*)(xb);
                float2 a1 = *(const float2*)(xb + W);
                float2 a2 = *(const float2*)(xb + H*W);
                float2 a3 = *(const float2*)(xb + H*W + W);
                float s = a0.x*a0.x + a0.y*a0.y + a1.x*a1.x + a1.y*a1.y
                        + a2.x*a2.x + a2.y*a2.y + a3.x*a3.x + a3.y*a3.y;
                pk[c] = (__bf16)sqrtf(s);
            }
            *(bf16x8*)&Pl[(i*128 + wp)*16 + dph*8] = pk;
        }
        bf16x8 z = {};
        *(bf16x8*)&Pl[(8*128 + wp)*16 + dph*8] = z;    // zero row for tap 9
    }

    // ---- B staging, reordered: Blds[o][tap*16+mc] = W[o][mc*9+tap]; tap 9 = 0 ----
    {
        int o = t & 127, kh = t >> 7;
#pragma unroll 4
        for (int kk = 0; kk < 80; kk++) {
            int kn = kh*80 + kk;
            int tap = kn >> 4, mc = kn & 15;
            float v = (tap < 9) ? lin_w[o*PATCH + mc*9 + tap] : 0.f;
            Blds[o*BROW + kn] = (__bf16)v;
        }
    }

    float lb[8];
#pragma unroll
    for (int nt = 0; nt < 8; nt++) lb[nt] = lin_b[nt*16 + l16];

    __syncthreads();

    float srun[8] = {0,0,0,0,0,0,0,0};
    int h8 = (quad & 1) * 8;
    int m0 = wave * 32 + l16;

    for (int hh = 0; hh < HOG; hh++) {
        f32x4 acc[2][8] = {};
#pragma unroll
        for (int ks = 0; ks < 5; ks++) {
            int tap = 2*ks + (quad >> 1);        // per-lane, hoisted (ks unrolled)
            int it = (tap * 11) >> 5;            // tap/3 for tap<10
            int jt = tap - it * 3;               // tap%3
            bf16x8 afr[2];
#pragma unroll
            for (int mt = 0; mt < 2; mt++) {
                int m = m0 + mt*16;
                afr[mt] = *(const bf16x8*)&Pl[((hh + it)*128 + m + jt)*16 + h8];
            }
#pragma unroll
            for (int nt = 0; nt < 8; nt++) {
                bf16x8 bfr = *(const bf16x8*)&Blds[(nt*16 + l16)*BROW + ks*32 + quad*8];
                acc[0][nt] = __builtin_amdgcn_mfma_f32_16x16x32_bf16(afr[0], bfr, acc[0][nt], 0, 0, 0);
                acc[1][nt] = __builtin_amdgcn_mfma_f32_16x16x32_bf16(afr[1], bfr, acc[1][nt], 0, 0, 0);
            }
        }
        // epilogue: bias + CELU + mask + reduce over patch rows
#pragma unroll
        for (int nt = 0; nt < 8; nt++) {
            float s = 0.f;
#pragma unroll
            for (int mt = 0; mt < 2; mt++) {
                int mb = wave*32 + mt*16 + quad*4;
#pragma unroll
                for (int r = 0; r < 4; r++) {
                    float p = acc[mt][nt][r] + lb[nt];
                    float a = (p > 0.f) ? p : (__expf(p) - 1.f);
                    if (mb + r < WO) s += a;
                }
            }
            s += __shfl_xor(s, 16, 64);
            s += __shfl_xor(s, 32, 64);
            srun[nt] += s;
        }
    }

    __syncthreads();                       // all P/B reads done; alias red over P
    float* red = (float*)smem;
    if (quad == 0) {
#pragma unroll
        for (int nt = 0; nt < 8; nt++) red[wave*OUTD + nt*16 + l16] = srun[nt];
    }
    __syncthreads();
    if (t < OUTD) {
        float tot = red[t] + red[OUTD+t] + red[2*OUTD+t] + red[3*OUTD+t];
        atomicAdd(&accg[n*OUTD + t], tot);
    }
}

// ---------------- mean + clamped L2 normalize ------------------------------
__global__ void finalize_kernel(const float* __restrict__ acc, float* __restrict__ out) {
    int n = blockIdx.x;
    int o = threadIdx.x;     // 128 threads
    float a = acc[n * OUTD + o] * (1.0f / (float)NL);
    float s = a * a;
#pragma unroll
    for (int off = 32; off > 0; off >>= 1) s += __shfl_down(s, off, 64);
    __shared__ float partial[2];
    if ((o & 63) == 0) partial[o >> 6] = s;
    __syncthreads();
    float norm = sqrtf(partial[0] + partial[1]);
    norm = fmaxf(norm, 1e-6f);
    out[n * OUTD + o] = a / norm;
}

extern "C" void kernel_launch(void* const* d_in, const int* in_sizes, int n_in,
                              void* d_out, int out_size, void* d_ws, size_t ws_size,
                              hipStream_t stream) {
    const float* x     = (const float*)d_in[0];
    const float* lin_w = (const float*)d_in[1];
    const float* lin_b = (const float*)d_in[2];
    float* out = (float*)d_out;

    float* acc = (float*)d_ws;   // 32*128 floats

    hipMemsetAsync(acc, 0, NB * OUTD * sizeof(float), stream);
    fused_kernel<<<NB * NGRP, 256, 0, stream>>>(x, lin_w, lin_b, acc);
    finalize_kernel<<<NB, OUTD, 0, stream>>>(acc, out);
}